// Round 1
// 183.241 us; speedup vs baseline: 1.0136x; 1.0136x over previous
//
#include <hip/hip_runtime.h>

// QuantizedBn2d (per-cluster quantized batchnorm requant), bit==8.
// Shapes: x[B=32, C=256, H=56, W=56] (int-valued fp32), params per cluster K=8.
//
// Semantics note: the reference runs under JAX with x64 DISABLED, so every
// .astype(jnp.int64) is int32 and the gemmlowp high-mul WRAPS in int32.
// Under wrap, mul = (prod+nudge)>>31 is always in {0,-1}; the rounding
// right-shift by post then collapses to:
//     r = (post < 2) ? mul : 0     (verified case-by-case for mul in {0,-1})
// and with z3 in [-64,63], tot = z3 + r is in [-65,63] -> 8-bit clamp is a
// provable no-op. We keep exact int32-wrap semantics via unsigned arithmetic.
//
// Memory-bound elementwise: ~206 MB traffic -> kernel floor ~31us @ 6.6 TB/s.
//
// V2 structure: one (b,c) plane per block (8192 blocks x 256 threads).
//  - plane = blockIdx.x: all 7 param loads are block-uniform -> scalar loads,
//    and the per-thread magic-mul divide (base/3136) is gone from the
//    address path.
//  - each thread issues its 3 (+1 tail) independent 16B loads up front for
//    memory-level parallelism, then computes and stores.

#define BB 32
#define CC 256
#define HWN 3136               // 56*56 elements per plane
#define PLANE_Q4 784           // float4s per plane (3136/4)
#define NPLANES (BB * CC)      // 8192 blocks

typedef float f32x4 __attribute__((ext_vector_type(4)));  // true vector type:
// __builtin_nontemporal_* requires int/float/pointer or vector thereof.

__device__ __forceinline__ float qbn_elem(float xf, int m, int w, int b,
                                          int pre, int m0, int sel, int z3v) {
    int sub = ((int)xf - m) * w + b;                     // int32 subsum (no overflow)
    unsigned x32 = ((unsigned)sub) << pre;               // left-shift branch (neg shift)
    unsigned prod = x32 * (unsigned)m0;                  // int32 wraparound mul
    // nudge = prod>=0 ? 2^30 : 1-2^30 ; add with wrap
    int ps = ((int)prod) >> 31;                          // 0 or -1
    unsigned nudge = 0x40000000u + ((unsigned)ps & 0x80000001u);
    int mul = ((int)(prod + nudge)) >> 31;               // in {0,-1}
    int tot = z3v + (mul & sel);                         // sel = (post<2) ? -1 : 0
    return (float)tot;                                   // clamp provably no-op
}

__device__ __forceinline__ f32x4 qbn_vec(f32x4 xv, int m, int w, int b,
                                         int pre, int m0, int sel, int z3v) {
    f32x4 ov;
    ov.x = qbn_elem(xv.x, m, w, b, pre, m0, sel, z3v);
    ov.y = qbn_elem(xv.y, m, w, b, pre, m0, sel, z3v);
    ov.z = qbn_elem(xv.z, m, w, b, pre, m0, sel, z3v);
    ov.w = qbn_elem(xv.w, m, w, b, pre, m0, sel, z3v);
    return ov;
}

__global__ __launch_bounds__(256) void qbn_kernel(
    const float* __restrict__ x,
    const int* __restrict__ bc,
    const int* __restrict__ z3,
    const int* __restrict__ M0,
    const int* __restrict__ shift,
    const int* __restrict__ mean,
    const int* __restrict__ wds,
    const int* __restrict__ bias,
    float* __restrict__ out)
{
    int plane = blockIdx.x;               // (b*C + c), block-uniform
    int b = plane >> 8;                   // C == 256
    int c = plane & 255;

    int k   = bc[b];                      // cluster id — scalar load
    int m   = mean[(k << 8) + c];
    int w   = wds [(k << 8) + c];
    int bi  = bias[(k << 8) + c];
    int s   = shift[k];
    int pre  = s < 0 ? -s : 0;
    int post = s > 0 ?  s : 0;
    int sel  = (post < 2) ? -1 : 0;       // rounding-rshift collapse (see header)
    int m0  = M0[k];
    int z3v = z3[k];

    int t = threadIdx.x;
    const f32x4* xp = (const f32x4*)x + (size_t)plane * PLANE_Q4;
    f32x4*       op = (f32x4*)out      + (size_t)plane * PLANE_Q4;

    // Issue all independent loads first (784 = 3*256 + 16).
    f32x4 v0 = __builtin_nontemporal_load(xp + t);
    f32x4 v1 = __builtin_nontemporal_load(xp + t + 256);
    f32x4 v2 = __builtin_nontemporal_load(xp + t + 512);
    bool tail = (t < (PLANE_Q4 - 768));   // 16 threads handle the ragged tail
    f32x4 v3;
    if (tail) v3 = __builtin_nontemporal_load(xp + t + 768);

    f32x4 o0 = qbn_vec(v0, m, w, bi, pre, m0, sel, z3v);
    f32x4 o1 = qbn_vec(v1, m, w, bi, pre, m0, sel, z3v);
    f32x4 o2 = qbn_vec(v2, m, w, bi, pre, m0, sel, z3v);

    __builtin_nontemporal_store(o0, op + t);
    __builtin_nontemporal_store(o1, op + t + 256);
    __builtin_nontemporal_store(o2, op + t + 512);
    if (tail) {
        f32x4 o3 = qbn_vec(v3, m, w, bi, pre, m0, sel, z3v);
        __builtin_nontemporal_store(o3, op + t + 768);
    }
}

extern "C" void kernel_launch(void* const* d_in, const int* in_sizes, int n_in,
                              void* d_out, int out_size, void* d_ws, size_t ws_size,
                              hipStream_t stream) {
    const float* x   = (const float*)d_in[0];
    const int* bc    = (const int*)d_in[1];
    const int* z3    = (const int*)d_in[2];
    const int* M0    = (const int*)d_in[3];
    const int* shift = (const int*)d_in[4];
    const int* mean  = (const int*)d_in[5];
    const int* wds   = (const int*)d_in[6];
    const int* bias  = (const int*)d_in[7];
    float* out = (float*)d_out;

    dim3 grid(NPLANES);    // 8192 blocks, one (b,c) plane each
    dim3 block(256);
    qbn_kernel<<<grid, block, 0, stream>>>(x, bc, z3, M0, shift, mean, wds, bias, out);
}